// Round 4
// baseline (10465.485 us; speedup 1.0000x reference)
//
#include <hip/hip_runtime.h>
#include <math.h>

namespace {

constexpr int kT = 30, kS = 1024, kB = 16;
constexpr int kHW = 128 * 128;
constexpr int kNF = kB * kT;                            // 480 frames
constexpr float kDT = (float)(1.0 / 29.0);
constexpr size_t kMuElems = (size_t)kB * kT * kHW * 3;  // 23,592,960 floats

__device__ __forceinline__ float splus01(float x) {
  float sp = (x > 20.0f) ? x : log1pf(expf(x));
  return fminf(fmaxf(sp, 1e-6f), 1.0f);
}

// ---------------------------------------------------------------------------
// Scatter: winner[p] = max point index s mapping to pixel p (last-write-wins
// = numpy sequential assignment). winner pre-set to -1. OOB points dropped.
// ---------------------------------------------------------------------------
__global__ void k_scatter(const float* __restrict__ vids,
                          int* __restrict__ winner) {
  const int f = blockIdx.x;
  const float* fr = vids + (size_t)f * kS * 5;
  int* wf = winner + (size_t)f * kHW;
  for (int s = threadIdx.x; s < kS; s += blockDim.x) {
    const int i = (int)(fr[s * 5 + 0] * 128.0f);
    const int j = (int)(fr[s * 5 + 1] * 128.0f);
    if ((unsigned)i < 128u && (unsigned)j < 128u)
      atomicMax(wf + i * 128 + j, s);
  }
}

// ---------------------------------------------------------------------------
// Encoder pair: conv CIN->3 (+bias, relu) -> conv 3->3 (+bias). Channels
// gathered on the fly: ch<3 = clip(Y[winner],0,1); HAS_T: ch3 = const t;
// last ch = mask. 32x32 tile, 256 threads.
// ---------------------------------------------------------------------------
template <int CIN, bool HAS_T>
__global__ __launch_bounds__(256) void k_enc(
    const float* __restrict__ vids, const int* __restrict__ winner, int fstep,
    const float* __restrict__ w1, const float* __restrict__ b1,
    const float* __restrict__ w2, const float* __restrict__ b2,
    float* __restrict__ out) {
  __shared__ float sIn[CIN][36][36];
  __shared__ float sC1[3][34][34];
  __shared__ float sW1[3 * CIN * 9], sW2[81], sB1[3], sB2[3];

  const int tid = threadIdx.x;
  const int f = blockIdx.x >> 4;
  const int df = f * fstep;
  const int ty = ((blockIdx.x >> 2) & 3) * 32;
  const int tx = (blockIdx.x & 3) * 32;

  for (int i = tid; i < 3 * CIN * 9; i += 256) sW1[i] = w1[i];
  for (int i = tid; i < 81; i += 256) sW2[i] = w2[i];
  if (tid < 3) { sB1[tid] = b1[tid]; sB2[tid] = b2[tid]; }

  const int* win = winner + (size_t)df * kHW;
  const float* fr = vids + (size_t)df * kS * 5;
  const float tval = HAS_T ? (float)(df % kT) * kDT : 0.0f;

  for (int idx = tid; idx < CIN * 1296; idx += 256) {
    const int ch = idx / 1296, rem = idx - ch * 1296;
    const int r = rem / 36, c = rem - r * 36;
    const int gy = ty - 2 + r, gx = tx - 2 + c;
    float v = 0.0f;
    if ((unsigned)gy < 128u && (unsigned)gx < 128u) {
      const int p = gy * 128 + gx;
      const int wn = win[p];
      if (ch < 3) {
        v = (wn >= 0) ? fminf(fmaxf(fr[wn * 5 + 2 + ch], 0.0f), 1.0f) : 0.0f;
      } else if (HAS_T && ch == 3) {
        v = tval;
      } else {
        v = (wn >= 0) ? 1.0f : 0.0f;  // mask channel
      }
    }
    sIn[ch][r][c] = v;
  }
  __syncthreads();

  for (int pos = tid; pos < 34 * 34; pos += 256) {
    const int r = pos / 34, c = pos - (pos / 34) * 34;
    const int gy = ty - 1 + r, gx = tx - 1 + c;
    float a0 = sB1[0], a1 = sB1[1], a2 = sB1[2];
#pragma unroll
    for (int ic = 0; ic < CIN; ic++)
#pragma unroll
      for (int k = 0; k < 9; k++) {
        const float v = sIn[ic][r + k / 3][c + k % 3];
        a0 = fmaf(v, sW1[(0 * CIN + ic) * 9 + k], a0);
        a1 = fmaf(v, sW1[(1 * CIN + ic) * 9 + k], a1);
        a2 = fmaf(v, sW1[(2 * CIN + ic) * 9 + k], a2);
      }
    const bool inb = ((unsigned)gy < 128u) && ((unsigned)gx < 128u);
    sC1[0][r][c] = inb ? fmaxf(a0, 0.0f) : 0.0f;
    sC1[1][r][c] = inb ? fmaxf(a1, 0.0f) : 0.0f;
    sC1[2][r][c] = inb ? fmaxf(a2, 0.0f) : 0.0f;
  }
  __syncthreads();

  float* of = out + (size_t)f * 3 * kHW;
  for (int pos = tid; pos < 1024; pos += 256) {
    const int r = pos >> 5, c = pos & 31;
    float a0 = sB2[0], a1 = sB2[1], a2 = sB2[2];
#pragma unroll
    for (int ic = 0; ic < 3; ic++)
#pragma unroll
      for (int k = 0; k < 9; k++) {
        const float v = sC1[ic][r + k / 3][c + k % 3];
        a0 = fmaf(v, sW2[(0 * 3 + ic) * 9 + k], a0);
        a1 = fmaf(v, sW2[(1 * 3 + ic) * 9 + k], a1);
        a2 = fmaf(v, sW2[(2 * 3 + ic) * 9 + k], a2);
      }
    const int p = (ty + r) * 128 + (tx + c);
    of[p] = a0;
    of[kHW + p] = a1;
    of[2 * kHW + p] = a2;
  }
}

// ---------------------------------------------------------------------------
// Init decode: h -> conv 3->24 relu -> conv 24->6 -> mu0 (Mem) + t=0 outputs.
// No Dt scaling. 16x16 tile, 256 threads.
// ---------------------------------------------------------------------------
__global__ __launch_bounds__(256) void k_dec_init(
    const float* __restrict__ h,
    const float* __restrict__ w1, const float* __restrict__ b1,
    const float* __restrict__ w2, const float* __restrict__ b2,
    float* __restrict__ memOut, float* __restrict__ out) {
  __shared__ float sIn[3][20][20];
  __shared__ float sA[24][18][18];
  __shared__ float sW1[648], sW2[1296], sB1[24], sB2[6];

  const int tid = threadIdx.x;
  const int bb = blockIdx.x >> 6;
  const int tile = blockIdx.x & 63;
  const int ty = (tile >> 3) * 16, tx = (tile & 7) * 16;

  for (int i = tid; i < 648; i += 256) sW1[i] = w1[i];
  for (int i = tid; i < 1296; i += 256) sW2[i] = w2[i];
  if (tid < 24) sB1[tid] = b1[tid];
  if (tid < 6) sB2[tid] = b2[tid];

  const float* sf = h + (size_t)bb * 3 * kHW;
  for (int idx = tid; idx < 3 * 400; idx += 256) {
    const int ch = idx / 400, rem = idx - ch * 400;
    const int r = rem / 20, c = rem - r * 20;
    const int gy = ty - 2 + r, gx = tx - 2 + c;
    float v = 0.0f;
    if ((unsigned)gy < 128u && (unsigned)gx < 128u)
      v = sf[ch * kHW + gy * 128 + gx];
    sIn[ch][r][c] = v;
  }
  __syncthreads();

  for (int pos = tid; pos < 18 * 18; pos += 256) {
    const int r = pos / 18, c = pos - (pos / 18) * 18;
    const int gy = ty - 1 + r, gx = tx - 1 + c;
    const bool inb = ((unsigned)gy < 128u) && ((unsigned)gx < 128u);
    float gv[27];
#pragma unroll
    for (int ic = 0; ic < 3; ic++)
#pragma unroll
      for (int k = 0; k < 9; k++)
        gv[ic * 9 + k] = sIn[ic][r + k / 3][c + k % 3];
#pragma unroll
    for (int oc = 0; oc < 24; oc++) {
      float acc = sB1[oc];
#pragma unroll
      for (int q = 0; q < 27; q++) acc = fmaf(gv[q], sW1[oc * 27 + q], acc);
      sA[oc][r][c] = inb ? fmaxf(acc, 0.0f) : 0.0f;
    }
  }
  __syncthreads();

  {
    const int r = tid >> 4, c = tid & 15;
    const int p = (ty + r) * 128 + (tx + c);
    float ft[6];
#pragma unroll
    for (int oc = 0; oc < 6; oc++) ft[oc] = sB2[oc];
#pragma unroll
    for (int ic = 0; ic < 24; ic++) {
      float av[9];
#pragma unroll
      for (int k = 0; k < 9; k++) av[k] = sA[ic][r + k / 3][c + k % 3];
#pragma unroll
      for (int oc = 0; oc < 6; oc++)
#pragma unroll
        for (int k = 0; k < 9; k++)
          ft[oc] = fmaf(av[k], sW2[(oc * 24 + ic) * 9 + k], ft[oc]);
    }
    float* mo = memOut + (size_t)bb * 3 * kHW;
    const size_t ob = ((size_t)(bb * kT + 0) * kHW + p) * 3;
#pragma unroll
    for (int ch = 0; ch < 3; ch++) {
      const float mu = ft[ch];
      mo[ch * kHW + p] = mu;
      out[ob + ch] = mu;
      out[kMuElems + ob + ch] = splus01(ft[3 + ch]);
    }
  }
}

// ---------------------------------------------------------------------------
// Fused recurrent cell step t (1..T-1):
//   hc = (E[t-1]-E[t])/Dt ; g = conv(cat(Mem,hc), mg) ; a = relu(conv(g,cd1))
//   ft = conv(a, cd2) ; mu = ft[0:3]*Dt -> Mem_next + out ;
//   sig = clip(softplus(ft[3:6]*Dt), eps, 1).
// 16x16 tile, halo chain 22->20->18->16. 256 threads. ~56KB LDS, 2 blk/CU.
// ---------------------------------------------------------------------------
__global__ __launch_bounds__(256) void k_cell(
    const float* __restrict__ memIn, const float* __restrict__ E, int t,
    const float* __restrict__ mgw, const float* __restrict__ mgb,
    const float* __restrict__ cw1, const float* __restrict__ cb1,
    const float* __restrict__ cw2, const float* __restrict__ cb2,
    float* __restrict__ memOut, float* __restrict__ out) {
  __shared__ float sIn[6][22][22];
  __shared__ float sG[3][20][20];
  __shared__ float sA[24][18][18];
  __shared__ float sWg[162], sW1[648], sW2[1296];
  __shared__ float sBg[3], sB1[24], sB2[6];

  const int tid = threadIdx.x;
  const int bb = blockIdx.x >> 6;
  const int tile = blockIdx.x & 63;
  const int ty = (tile >> 3) * 16, tx = (tile & 7) * 16;

  for (int i = tid; i < 162; i += 256) sWg[i] = mgw[i];
  for (int i = tid; i < 648; i += 256) sW1[i] = cw1[i];
  for (int i = tid; i < 1296; i += 256) sW2[i] = cw2[i];
  if (tid < 3) sBg[tid] = mgb[tid];
  if (tid < 24) sB1[tid] = cb1[tid];
  if (tid < 6) sB2[tid] = cb2[tid];

  const float* mi = memIn + (size_t)bb * 3 * kHW;
  const float* Ep = E + (size_t)(bb * kT + t - 1) * 3 * kHW;
  const float* Ec = E + (size_t)(bb * kT + t) * 3 * kHW;

  for (int idx = tid; idx < 6 * 484; idx += 256) {
    const int ch = idx / 484, rem = idx - ch * 484;
    const int r = rem / 22, c = rem - r * 22;
    const int gy = ty - 3 + r, gx = tx - 3 + c;
    float v = 0.0f;
    if ((unsigned)gy < 128u && (unsigned)gx < 128u) {
      const int p = gy * 128 + gx;
      v = (ch < 3) ? mi[ch * kHW + p]
                   : (Ep[(ch - 3) * kHW + p] - Ec[(ch - 3) * kHW + p]) / kDT;
    }
    sIn[ch][r][c] = v;
  }
  __syncthreads();

  // g = conv(in, mg) + bias, no relu. 20x20, zero outside image.
  for (int pos = tid; pos < 20 * 20; pos += 256) {
    const int r = pos / 20, c = pos - (pos / 20) * 20;
    const int gy = ty - 2 + r, gx = tx - 2 + c;
    float a0 = sBg[0], a1 = sBg[1], a2 = sBg[2];
#pragma unroll
    for (int ic = 0; ic < 6; ic++)
#pragma unroll
      for (int k = 0; k < 9; k++) {
        const float v = sIn[ic][r + k / 3][c + k % 3];
        a0 = fmaf(v, sWg[(0 * 6 + ic) * 9 + k], a0);
        a1 = fmaf(v, sWg[(1 * 6 + ic) * 9 + k], a1);
        a2 = fmaf(v, sWg[(2 * 6 + ic) * 9 + k], a2);
      }
    const bool inb = ((unsigned)gy < 128u) && ((unsigned)gx < 128u);
    sG[0][r][c] = inb ? a0 : 0.0f;
    sG[1][r][c] = inb ? a1 : 0.0f;
    sG[2][r][c] = inb ? a2 : 0.0f;
  }
  __syncthreads();

  // a = relu(conv(g, cd1)). 18x18x24.
  for (int pos = tid; pos < 18 * 18; pos += 256) {
    const int r = pos / 18, c = pos - (pos / 18) * 18;
    const int gy = ty - 1 + r, gx = tx - 1 + c;
    const bool inb = ((unsigned)gy < 128u) && ((unsigned)gx < 128u);
    float gv[27];
#pragma unroll
    for (int ic = 0; ic < 3; ic++)
#pragma unroll
      for (int k = 0; k < 9; k++)
        gv[ic * 9 + k] = sG[ic][r + k / 3][c + k % 3];
#pragma unroll
    for (int oc = 0; oc < 24; oc++) {
      float acc = sB1[oc];
#pragma unroll
      for (int q = 0; q < 27; q++) acc = fmaf(gv[q], sW1[oc * 27 + q], acc);
      sA[oc][r][c] = inb ? fmaxf(acc, 0.0f) : 0.0f;
    }
  }
  __syncthreads();

  {
    const int r = tid >> 4, c = tid & 15;
    const int p = (ty + r) * 128 + (tx + c);
    float ft[6];
#pragma unroll
    for (int oc = 0; oc < 6; oc++) ft[oc] = sB2[oc];
#pragma unroll
    for (int ic = 0; ic < 24; ic++) {
      float av[9];
#pragma unroll
      for (int k = 0; k < 9; k++) av[k] = sA[ic][r + k / 3][c + k % 3];
#pragma unroll
      for (int oc = 0; oc < 6; oc++)
#pragma unroll
        for (int k = 0; k < 9; k++)
          ft[oc] = fmaf(av[k], sW2[(oc * 24 + ic) * 9 + k], ft[oc]);
    }
    float* mo = memOut + (size_t)bb * 3 * kHW;
    const size_t ob = ((size_t)(bb * kT + t) * kHW + p) * 3;
#pragma unroll
    for (int ch = 0; ch < 3; ch++) {
      const float mu = ft[ch] * kDT;
      mo[ch * kHW + p] = mu;
      out[ob + ch] = mu;
      out[kMuElems + ob + ch] = splus01(ft[3 + ch] * kDT);
    }
  }
}

}  // namespace

extern "C" void kernel_launch(void* const* d_in, const int* in_sizes, int n_in,
                              void* d_out, int out_size, void* d_ws,
                              size_t ws_size, hipStream_t stream) {
  const float* vids  = (const float*)d_in[0];
  const float* ie_w1 = (const float*)d_in[1];
  const float* ie_b1 = (const float*)d_in[2];
  const float* ie_w2 = (const float*)d_in[3];
  const float* ie_b2 = (const float*)d_in[4];
  const float* id_w1 = (const float*)d_in[5];
  const float* id_b1 = (const float*)d_in[6];
  const float* id_w2 = (const float*)d_in[7];
  const float* id_b2 = (const float*)d_in[8];
  const float* ce_w1 = (const float*)d_in[9];
  const float* ce_b1 = (const float*)d_in[10];
  const float* ce_w2 = (const float*)d_in[11];
  const float* ce_b2 = (const float*)d_in[12];
  const float* cd_w1 = (const float*)d_in[13];
  const float* cd_b1 = (const float*)d_in[14];
  const float* cd_w2 = (const float*)d_in[15];
  const float* cd_b2 = (const float*)d_in[16];
  const float* mg_w  = (const float*)d_in[17];
  const float* mg_b  = (const float*)d_in[18];

  char* ws = (char*)d_ws;
  int* winner = (int*)ws;   ws += (size_t)kNF * kHW * 4;       // 31.5 MB
  float* h    = (float*)ws; ws += (size_t)kB * 3 * kHW * 4;    // 3.1 MB
  float* memA = (float*)ws; ws += (size_t)kB * 3 * kHW * 4;    // 3.1 MB
  float* memB = (float*)ws; ws += (size_t)kB * 3 * kHW * 4;    // 3.1 MB
  float* E    = (float*)ws; ws += (size_t)kNF * 3 * kHW * 4;   // 94.4 MB

  float* out = (float*)d_out;  // float32: reference output dtype

  hipMemsetAsync(winner, 0xFF, (size_t)kNF * kHW * 4, stream);
  k_scatter<<<kNF, 256, 0, stream>>>(vids, winner);

  // E[b,t] = enc2(vid_t[b,t]) for all 480 frames (parallel).
  k_enc<5, true><<<kNF * 16, 256, 0, stream>>>(vids, winner, 1, ce_w1, ce_b1,
                                               ce_w2, ce_b2, E);
  // h[b] = init encoder on frame (b, 0); reuses that frame's scatter.
  k_enc<4, false><<<kB * 16, 256, 0, stream>>>(vids, winner, kT, ie_w1, ie_b1,
                                               ie_w2, ie_b2, h);
  // init decode: mu0 -> memA + outputs at t=0.
  k_dec_init<<<kB * 64, 256, 0, stream>>>(h, id_w1, id_b1, id_w2, id_b2, memA,
                                          out);

  // Sequential recurrence, ping-pong Mem buffers.
  float* bufs[2] = {memA, memB};
  for (int t = 1; t < kT; ++t) {
    k_cell<<<kB * 64, 256, 0, stream>>>(bufs[(t + 1) & 1], E, t, mg_w, mg_b,
                                        cd_w1, cd_b1, cd_w2, cd_b2,
                                        bufs[t & 1], out);
  }
}

// Round 5
// 1858.257 us; speedup vs baseline: 5.6319x; 5.6319x over previous
//
#include <hip/hip_runtime.h>
#include <math.h>

namespace {

constexpr int kT = 30, kS = 1024, kB = 16;
constexpr int kHW = 128 * 128;
constexpr int kNF = kB * kT;                            // 480 frames
constexpr float kDT = (float)(1.0 / 29.0);
constexpr size_t kMuElems = (size_t)kB * kT * kHW * 3;  // 23,592,960 floats

__device__ __forceinline__ float splus01(float x) {
  float sp = (x > 20.0f) ? x : log1pf(expf(x));
  return fminf(fmaxf(sp, 1e-6f), 1.0f);
}

// ---------------------------------------------------------------------------
// Scatter: winner[p] = max point index s mapping to pixel p (last-write-wins
// = numpy sequential assignment). winner pre-set to -1. OOB points dropped.
// ---------------------------------------------------------------------------
__global__ void k_scatter(const float* __restrict__ vids,
                          int* __restrict__ winner) {
  const int f = blockIdx.x;
  const float* fr = vids + (size_t)f * kS * 5;
  int* wf = winner + (size_t)f * kHW;
  for (int s = threadIdx.x; s < kS; s += blockDim.x) {
    const int i = (int)(fr[s * 5 + 0] * 128.0f);
    const int j = (int)(fr[s * 5 + 1] * 128.0f);
    if ((unsigned)i < 128u && (unsigned)j < 128u)
      atomicMax(wf + i * 128 + j, s);
  }
}

// ---------------------------------------------------------------------------
// Encoder pair: conv CIN->3 (+bias, relu) -> conv 3->3 (+bias). Channels
// gathered on the fly. 32x32 tile, 256 threads. (Unchanged from passing r4.)
// ---------------------------------------------------------------------------
template <int CIN, bool HAS_T>
__global__ __launch_bounds__(256) void k_enc(
    const float* __restrict__ vids, const int* __restrict__ winner, int fstep,
    const float* __restrict__ w1, const float* __restrict__ b1,
    const float* __restrict__ w2, const float* __restrict__ b2,
    float* __restrict__ out) {
  __shared__ float sIn[CIN][36][36];
  __shared__ float sC1[3][34][34];
  __shared__ float sW1[3 * CIN * 9], sW2[81], sB1[3], sB2[3];

  const int tid = threadIdx.x;
  const int f = blockIdx.x >> 4;
  const int df = f * fstep;
  const int ty = ((blockIdx.x >> 2) & 3) * 32;
  const int tx = (blockIdx.x & 3) * 32;

  for (int i = tid; i < 3 * CIN * 9; i += 256) sW1[i] = w1[i];
  for (int i = tid; i < 81; i += 256) sW2[i] = w2[i];
  if (tid < 3) { sB1[tid] = b1[tid]; sB2[tid] = b2[tid]; }

  const int* win = winner + (size_t)df * kHW;
  const float* fr = vids + (size_t)df * kS * 5;
  const float tval = HAS_T ? (float)(df % kT) * kDT : 0.0f;

  for (int idx = tid; idx < CIN * 1296; idx += 256) {
    const int ch = idx / 1296, rem = idx - ch * 1296;
    const int r = rem / 36, c = rem - r * 36;
    const int gy = ty - 2 + r, gx = tx - 2 + c;
    float v = 0.0f;
    if ((unsigned)gy < 128u && (unsigned)gx < 128u) {
      const int p = gy * 128 + gx;
      const int wn = win[p];
      if (ch < 3) {
        v = (wn >= 0) ? fminf(fmaxf(fr[wn * 5 + 2 + ch], 0.0f), 1.0f) : 0.0f;
      } else if (HAS_T && ch == 3) {
        v = tval;
      } else {
        v = (wn >= 0) ? 1.0f : 0.0f;  // mask channel
      }
    }
    sIn[ch][r][c] = v;
  }
  __syncthreads();

  for (int pos = tid; pos < 34 * 34; pos += 256) {
    const int r = pos / 34, c = pos - (pos / 34) * 34;
    const int gy = ty - 1 + r, gx = tx - 1 + c;
    float a0 = sB1[0], a1 = sB1[1], a2 = sB1[2];
#pragma unroll
    for (int ic = 0; ic < CIN; ic++)
#pragma unroll
      for (int k = 0; k < 9; k++) {
        const float v = sIn[ic][r + k / 3][c + k % 3];
        a0 = fmaf(v, sW1[(0 * CIN + ic) * 9 + k], a0);
        a1 = fmaf(v, sW1[(1 * CIN + ic) * 9 + k], a1);
        a2 = fmaf(v, sW1[(2 * CIN + ic) * 9 + k], a2);
      }
    const bool inb = ((unsigned)gy < 128u) && ((unsigned)gx < 128u);
    sC1[0][r][c] = inb ? fmaxf(a0, 0.0f) : 0.0f;
    sC1[1][r][c] = inb ? fmaxf(a1, 0.0f) : 0.0f;
    sC1[2][r][c] = inb ? fmaxf(a2, 0.0f) : 0.0f;
  }
  __syncthreads();

  float* of = out + (size_t)f * 3 * kHW;
  for (int pos = tid; pos < 1024; pos += 256) {
    const int r = pos >> 5, c = pos & 31;
    float a0 = sB2[0], a1 = sB2[1], a2 = sB2[2];
#pragma unroll
    for (int ic = 0; ic < 3; ic++)
#pragma unroll
      for (int k = 0; k < 9; k++) {
        const float v = sC1[ic][r + k / 3][c + k % 3];
        a0 = fmaf(v, sW2[(0 * 3 + ic) * 9 + k], a0);
        a1 = fmaf(v, sW2[(1 * 3 + ic) * 9 + k], a1);
        a2 = fmaf(v, sW2[(2 * 3 + ic) * 9 + k], a2);
      }
    const int p = (ty + r) * 128 + (tx + c);
    of[p] = a0;
    of[kHW + p] = a1;
    of[2 * kHW + p] = a2;
  }
}

// ---------------------------------------------------------------------------
// In-place temporal difference: E[t] <- (E[t-1] - E[t]) / Dt for t=1..T-1.
// One thread per (b, ch, pixel) strand; sequential in t within the thread so
// no cross-thread ordering is needed. E[0] left as-is (unused afterwards).
// ---------------------------------------------------------------------------
__global__ __launch_bounds__(256) void k_hc(float* __restrict__ E) {
  const int idx = blockIdx.x * 256 + threadIdx.x;
  if (idx >= kB * 3 * kHW) return;
  const int b = idx / (3 * kHW);
  const int rem = idx - b * 3 * kHW;
  float* base = E + (size_t)b * kT * 3 * kHW + rem;
  float prev = base[0];
  for (int t = 1; t < kT; ++t) {
    const size_t o = (size_t)t * 3 * kHW;
    const float cur = base[o];
    base[o] = (prev - cur) / kDT;
    prev = cur;
  }
}

// ---------------------------------------------------------------------------
// Init decode: h -> conv 3->24 relu -> conv 24->6 -> mu0 (Mem) + t=0 outputs.
// (Unchanged from passing r4; runs once, ~15us.)
// ---------------------------------------------------------------------------
__global__ __launch_bounds__(256) void k_dec_init(
    const float* __restrict__ h,
    const float* __restrict__ w1, const float* __restrict__ b1,
    const float* __restrict__ w2, const float* __restrict__ b2,
    float* __restrict__ memOut, float* __restrict__ out) {
  __shared__ float sIn[3][20][20];
  __shared__ float sA[24][18][18];
  __shared__ float sW1[648], sW2[1296], sB1[24], sB2[6];

  const int tid = threadIdx.x;
  const int bb = blockIdx.x >> 6;
  const int tile = blockIdx.x & 63;
  const int ty = (tile >> 3) * 16, tx = (tile & 7) * 16;

  for (int i = tid; i < 648; i += 256) sW1[i] = w1[i];
  for (int i = tid; i < 1296; i += 256) sW2[i] = w2[i];
  if (tid < 24) sB1[tid] = b1[tid];
  if (tid < 6) sB2[tid] = b2[tid];

  const float* sf = h + (size_t)bb * 3 * kHW;
  for (int idx = tid; idx < 3 * 400; idx += 256) {
    const int ch = idx / 400, rem = idx - ch * 400;
    const int r = rem / 20, c = rem - r * 20;
    const int gy = ty - 2 + r, gx = tx - 2 + c;
    float v = 0.0f;
    if ((unsigned)gy < 128u && (unsigned)gx < 128u)
      v = sf[ch * kHW + gy * 128 + gx];
    sIn[ch][r][c] = v;
  }
  __syncthreads();

  for (int pos = tid; pos < 18 * 18; pos += 256) {
    const int r = pos / 18, c = pos - (pos / 18) * 18;
    const int gy = ty - 1 + r, gx = tx - 1 + c;
    const bool inb = ((unsigned)gy < 128u) && ((unsigned)gx < 128u);
    float gv[27];
#pragma unroll
    for (int ic = 0; ic < 3; ic++)
#pragma unroll
      for (int k = 0; k < 9; k++)
        gv[ic * 9 + k] = sIn[ic][r + k / 3][c + k % 3];
#pragma unroll
    for (int oc = 0; oc < 24; oc++) {
      float acc = sB1[oc];
#pragma unroll
      for (int q = 0; q < 27; q++) acc = fmaf(gv[q], sW1[oc * 27 + q], acc);
      sA[oc][r][c] = inb ? fmaxf(acc, 0.0f) : 0.0f;
    }
  }
  __syncthreads();

  {
    const int r = tid >> 4, c = tid & 15;
    const int p = (ty + r) * 128 + (tx + c);
    float ft[6];
#pragma unroll
    for (int oc = 0; oc < 6; oc++) ft[oc] = sB2[oc];
#pragma unroll
    for (int ic = 0; ic < 24; ic++) {
      float av[9];
#pragma unroll
      for (int k = 0; k < 9; k++) av[k] = sA[ic][r + k / 3][c + k % 3];
#pragma unroll
      for (int oc = 0; oc < 6; oc++)
#pragma unroll
        for (int k = 0; k < 9; k++)
          ft[oc] = fmaf(av[k], sW2[(oc * 24 + ic) * 9 + k], ft[oc]);
    }
    float* mo = memOut + (size_t)bb * 3 * kHW;
    const size_t ob = ((size_t)(bb * kT + 0) * kHW + p) * 3;
#pragma unroll
    for (int ch = 0; ch < 3; ch++) {
      const float mu = ft[ch];
      mo[ch * kHW + p] = mu;
      out[ob + ch] = mu;
      out[kMuElems + ob + ch] = splus01(ft[3 + ch]);
    }
  }
}

// ---------------------------------------------------------------------------
// Fused recurrent cell, occupancy-optimized:
//   sIn = [Mem(3ch) | hc(3ch, precomputed in E)] with 3-halo
//   sG  = conv6->3(mg)        (20x20)
//   sA  = relu(conv3->24(cd1)) in TWO passes of 12 channels (18x18x12 LDS)
//   ft  = conv24->6(cd2) accumulated in registers across the two passes
// LDS ~32KB (was 56KB), weights via wave-uniform scalar loads (s_load),
// __launch_bounds__(256,4) caps VGPRs at 128. Target 4 blocks/CU.
// ---------------------------------------------------------------------------
__global__ __launch_bounds__(256, 4) void k_cell(
    const float* __restrict__ memIn, const float* __restrict__ E, int t,
    const float* __restrict__ mgw, const float* __restrict__ mgb,
    const float* __restrict__ cw1, const float* __restrict__ cb1,
    const float* __restrict__ cw2, const float* __restrict__ cb2,
    float* __restrict__ memOut, float* __restrict__ out) {
  __shared__ float sIn[6][22][22];   // 11.6 KB
  __shared__ float sG[3][20][20];    //  4.7 KB
  __shared__ float sA[12][18][18];   // 15.2 KB (channel-split, 2 passes)

  const int tid = threadIdx.x;
  const int bb = blockIdx.x >> 6;
  const int tile = blockIdx.x & 63;
  const int ty = (tile >> 3) * 16, tx = (tile & 7) * 16;

  const float* mi = memIn + (size_t)bb * 3 * kHW;
  const float* hc = E + (size_t)(bb * kT + t) * 3 * kHW;  // precomputed diff

  // Stage 6x22x22 input (3-halo). Zero outside image.
  for (int idx = tid; idx < 6 * 484; idx += 256) {
    const int ch = idx / 484, rem = idx - ch * 484;
    const int r = rem / 22, c = rem - r * 22;
    const int gy = ty - 3 + r, gx = tx - 3 + c;
    float v = 0.0f;
    if ((unsigned)gy < 128u && (unsigned)gx < 128u) {
      const int p = gy * 128 + gx;
      v = (ch < 3) ? mi[ch * kHW + p] : hc[(ch - 3) * kHW + p];
    }
    sIn[ch][r][c] = v;
  }
  __syncthreads();

  // sG = conv(sIn, mg) + bias (no relu), 20x20, zero outside image.
  for (int pos = tid; pos < 20 * 20; pos += 256) {
    const int r = pos / 20, c = pos - (pos / 20) * 20;
    const int gy = ty - 2 + r, gx = tx - 2 + c;
    float a0 = mgb[0], a1 = mgb[1], a2 = mgb[2];
#pragma unroll
    for (int ic = 0; ic < 6; ic++)
#pragma unroll
      for (int k = 0; k < 9; k++) {
        const float v = sIn[ic][r + k / 3][c + k % 3];
        a0 = fmaf(v, mgw[(0 * 6 + ic) * 9 + k], a0);
        a1 = fmaf(v, mgw[(1 * 6 + ic) * 9 + k], a1);
        a2 = fmaf(v, mgw[(2 * 6 + ic) * 9 + k], a2);
      }
    const bool inb = ((unsigned)gy < 128u) && ((unsigned)gx < 128u);
    sG[0][r][c] = inb ? a0 : 0.0f;
    sG[1][r][c] = inb ? a1 : 0.0f;
    sG[2][r][c] = inb ? a2 : 0.0f;
  }
  __syncthreads();

  const int r = tid >> 4, c = tid & 15;
  float ft[6];
#pragma unroll
  for (int oc = 0; oc < 6; oc++) ft[oc] = cb2[oc];

  for (int pass = 0; pass < 2; ++pass) {
    // conv1 (cd1) for 12 output channels of this pass -> sA.
    for (int pos = tid; pos < 18 * 18; pos += 256) {
      const int pr = pos / 18, pc = pos - (pos / 18) * 18;
      const int gy = ty - 1 + pr, gx = tx - 1 + pc;
      const bool inb = ((unsigned)gy < 128u) && ((unsigned)gx < 128u);
      float gv[27];
#pragma unroll
      for (int ic = 0; ic < 3; ic++)
#pragma unroll
        for (int k = 0; k < 9; k++)
          gv[ic * 9 + k] = sG[ic][pr + k / 3][pc + k % 3];
      for (int ol = 0; ol < 12; ol++) {
        const int oc = pass * 12 + ol;
        float acc = cb1[oc];
#pragma unroll
        for (int q = 0; q < 27; q++) acc = fmaf(gv[q], cw1[oc * 27 + q], acc);
        sA[ol][pr][pc] = inb ? fmaxf(acc, 0.0f) : 0.0f;
      }
    }
    __syncthreads();

    // conv2 (cd2): accumulate this pass's 12 input channels into ft.
    for (int il = 0; il < 12; il++) {
      const int ic = pass * 12 + il;
      float av[9];
#pragma unroll
      for (int k = 0; k < 9; k++) av[k] = sA[il][r + k / 3][c + k % 3];
#pragma unroll
      for (int oc = 0; oc < 6; oc++)
#pragma unroll
        for (int k = 0; k < 9; k++)
          ft[oc] = fmaf(av[k], cw2[(oc * 24 + ic) * 9 + k], ft[oc]);
    }
    __syncthreads();  // before next pass overwrites sA
  }

  {
    const int p = (ty + r) * 128 + (tx + c);
    float* mo = memOut + (size_t)bb * 3 * kHW;
    const size_t ob = ((size_t)(bb * kT + t) * kHW + p) * 3;
#pragma unroll
    for (int ch = 0; ch < 3; ch++) {
      const float mu = ft[ch] * kDT;
      mo[ch * kHW + p] = mu;
      out[ob + ch] = mu;
      out[kMuElems + ob + ch] = splus01(ft[3 + ch] * kDT);
    }
  }
}

}  // namespace

extern "C" void kernel_launch(void* const* d_in, const int* in_sizes, int n_in,
                              void* d_out, int out_size, void* d_ws,
                              size_t ws_size, hipStream_t stream) {
  const float* vids  = (const float*)d_in[0];
  const float* ie_w1 = (const float*)d_in[1];
  const float* ie_b1 = (const float*)d_in[2];
  const float* ie_w2 = (const float*)d_in[3];
  const float* ie_b2 = (const float*)d_in[4];
  const float* id_w1 = (const float*)d_in[5];
  const float* id_b1 = (const float*)d_in[6];
  const float* id_w2 = (const float*)d_in[7];
  const float* id_b2 = (const float*)d_in[8];
  const float* ce_w1 = (const float*)d_in[9];
  const float* ce_b1 = (const float*)d_in[10];
  const float* ce_w2 = (const float*)d_in[11];
  const float* ce_b2 = (const float*)d_in[12];
  const float* cd_w1 = (const float*)d_in[13];
  const float* cd_b1 = (const float*)d_in[14];
  const float* cd_w2 = (const float*)d_in[15];
  const float* cd_b2 = (const float*)d_in[16];
  const float* mg_w  = (const float*)d_in[17];
  const float* mg_b  = (const float*)d_in[18];

  char* ws = (char*)d_ws;
  int* winner = (int*)ws;   ws += (size_t)kNF * kHW * 4;       // 31.5 MB
  float* h    = (float*)ws; ws += (size_t)kB * 3 * kHW * 4;    // 3.1 MB
  float* memA = (float*)ws; ws += (size_t)kB * 3 * kHW * 4;    // 3.1 MB
  float* memB = (float*)ws; ws += (size_t)kB * 3 * kHW * 4;    // 3.1 MB
  float* E    = (float*)ws; ws += (size_t)kNF * 3 * kHW * 4;   // 94.4 MB

  float* out = (float*)d_out;  // float32 (reference output dtype)

  hipMemsetAsync(winner, 0xFF, (size_t)kNF * kHW * 4, stream);
  k_scatter<<<kNF, 256, 0, stream>>>(vids, winner);

  // E[b,t] = enc2(vid_t[b,t]) for all 480 frames (parallel).
  k_enc<5, true><<<kNF * 16, 256, 0, stream>>>(vids, winner, 1, ce_w1, ce_b1,
                                               ce_w2, ce_b2, E);
  // In-place: E[t] <- (E[t-1]-E[t])/Dt  (t>=1).
  k_hc<<<(kB * 3 * kHW + 255) / 256, 256, 0, stream>>>(E);

  // h[b] = init encoder on frame (b, 0).
  k_enc<4, false><<<kB * 16, 256, 0, stream>>>(vids, winner, kT, ie_w1, ie_b1,
                                               ie_w2, ie_b2, h);
  // init decode: mu0 -> memA + outputs at t=0.
  k_dec_init<<<kB * 64, 256, 0, stream>>>(h, id_w1, id_b1, id_w2, id_b2, memA,
                                          out);

  // Sequential recurrence, ping-pong Mem buffers.
  float* bufs[2] = {memA, memB};
  for (int t = 1; t < kT; ++t) {
    k_cell<<<kB * 64, 256, 0, stream>>>(bufs[(t + 1) & 1], E, t, mg_w, mg_b,
                                        cd_w1, cd_b1, cd_w2, cd_b2,
                                        bufs[t & 1], out);
  }
}

// Round 7
// 1420.484 us; speedup vs baseline: 7.3675x; 1.3082x over previous
//
#include <hip/hip_runtime.h>
#include <math.h>

namespace {

constexpr int kT = 30, kS = 1024, kB = 16;
constexpr int kHW = 128 * 128;
constexpr int kNF = kB * kT;                            // 480 frames
constexpr float kDT = (float)(1.0 / 29.0);
constexpr size_t kMuElems = (size_t)kB * kT * kHW * 3;  // 23,592,960 floats

__device__ __forceinline__ float splus01(float x) {
  float sp = (x > 20.0f) ? x : log1pf(expf(x));
  return fminf(fmaxf(sp, 1e-6f), 1.0f);
}

// ---------------------------------------------------------------------------
// Scatter: winner[p] = max point index s mapping to pixel p (last-write-wins
// = numpy sequential assignment). winner pre-set to -1. OOB points dropped.
// ---------------------------------------------------------------------------
__global__ void k_scatter(const float* __restrict__ vids,
                          int* __restrict__ winner) {
  const int f = blockIdx.x;
  const float* fr = vids + (size_t)f * kS * 5;
  int* wf = winner + (size_t)f * kHW;
  for (int s = threadIdx.x; s < kS; s += blockDim.x) {
    const int i = (int)(fr[s * 5 + 0] * 128.0f);
    const int j = (int)(fr[s * 5 + 1] * 128.0f);
    if ((unsigned)i < 128u && (unsigned)j < 128u)
      atomicMax(wf + i * 128 + j, s);
  }
}

// ---------------------------------------------------------------------------
// Encoder pair: conv CIN->3 (+bias, relu) -> conv 3->3 (+bias). Channels
// gathered on the fly. 32x32 tile, 256 threads. Weights via wave-uniform
// scalar loads (no LDS staging); launch_bounds(256,4) -> VGPR<=128.
// ---------------------------------------------------------------------------
template <int CIN, bool HAS_T>
__global__ __launch_bounds__(256, 4) void k_enc(
    const float* __restrict__ vids, const int* __restrict__ winner, int fstep,
    const float* __restrict__ w1, const float* __restrict__ b1,
    const float* __restrict__ w2, const float* __restrict__ b2,
    float* __restrict__ out) {
  __shared__ float sIn[CIN][36][36];
  __shared__ float sC1[3][34][34];

  const int tid = threadIdx.x;
  const int f = blockIdx.x >> 4;
  const int df = f * fstep;
  const int ty = ((blockIdx.x >> 2) & 3) * 32;
  const int tx = (blockIdx.x & 3) * 32;

  const int* win = winner + (size_t)df * kHW;
  const float* fr = vids + (size_t)df * kS * 5;
  const float tval = HAS_T ? (float)(df % kT) * kDT : 0.0f;

  for (int idx = tid; idx < CIN * 1296; idx += 256) {
    const int ch = idx / 1296, rem = idx - ch * 1296;
    const int r = rem / 36, c = rem - r * 36;
    const int gy = ty - 2 + r, gx = tx - 2 + c;
    float v = 0.0f;
    if ((unsigned)gy < 128u && (unsigned)gx < 128u) {
      const int p = gy * 128 + gx;
      const int wn = win[p];
      if (ch < 3) {
        v = (wn >= 0) ? fminf(fmaxf(fr[wn * 5 + 2 + ch], 0.0f), 1.0f) : 0.0f;
      } else if (HAS_T && ch == 3) {
        v = tval;
      } else {
        v = (wn >= 0) ? 1.0f : 0.0f;  // mask channel
      }
    }
    sIn[ch][r][c] = v;
  }
  __syncthreads();

  for (int pos = tid; pos < 34 * 34; pos += 256) {
    const int r = pos / 34, c = pos - (pos / 34) * 34;
    const int gy = ty - 1 + r, gx = tx - 1 + c;
    float a0 = b1[0], a1 = b1[1], a2 = b1[2];
#pragma unroll
    for (int ic = 0; ic < CIN; ic++)
#pragma unroll
      for (int k = 0; k < 9; k++) {
        const float v = sIn[ic][r + k / 3][c + k % 3];
        a0 = fmaf(v, w1[(0 * CIN + ic) * 9 + k], a0);
        a1 = fmaf(v, w1[(1 * CIN + ic) * 9 + k], a1);
        a2 = fmaf(v, w1[(2 * CIN + ic) * 9 + k], a2);
      }
    const bool inb = ((unsigned)gy < 128u) && ((unsigned)gx < 128u);
    sC1[0][r][c] = inb ? fmaxf(a0, 0.0f) : 0.0f;
    sC1[1][r][c] = inb ? fmaxf(a1, 0.0f) : 0.0f;
    sC1[2][r][c] = inb ? fmaxf(a2, 0.0f) : 0.0f;
  }
  __syncthreads();

  float* of = out + (size_t)f * 3 * kHW;
  for (int pos = tid; pos < 1024; pos += 256) {
    const int r = pos >> 5, c = pos & 31;
    float a0 = b2[0], a1 = b2[1], a2 = b2[2];
#pragma unroll
    for (int ic = 0; ic < 3; ic++)
#pragma unroll
      for (int k = 0; k < 9; k++) {
        const float v = sC1[ic][r + k / 3][c + k % 3];
        a0 = fmaf(v, w2[(0 * 3 + ic) * 9 + k], a0);
        a1 = fmaf(v, w2[(1 * 3 + ic) * 9 + k], a1);
        a2 = fmaf(v, w2[(2 * 3 + ic) * 9 + k], a2);
      }
    const int p = (ty + r) * 128 + (tx + c);
    of[p] = a0;
    of[kHW + p] = a1;
    of[2 * kHW + p] = a2;
  }
}

// ---------------------------------------------------------------------------
// In-place temporal difference: E[t] <- (E[t-1] - E[t]) / Dt for t=1..T-1.
// One thread per (b, ch, pixel) strand; sequential in t within the thread.
// ---------------------------------------------------------------------------
__global__ __launch_bounds__(256) void k_hc(float* __restrict__ E) {
  const int idx = blockIdx.x * 256 + threadIdx.x;
  if (idx >= kB * 3 * kHW) return;
  const int b = idx / (3 * kHW);
  const int rem = idx - b * 3 * kHW;
  float* base = E + (size_t)b * kT * 3 * kHW + rem;
  float prev = base[0];
  for (int t = 1; t < kT; ++t) {
    const size_t o = (size_t)t * 3 * kHW;
    const float cur = base[o];
    base[o] = (prev - cur) / kDT;
    prev = cur;
  }
}

// ---------------------------------------------------------------------------
// Init decode (occupancy-optimized): h -> conv 3->24 relu (2 passes of 12)
// -> conv 24->6 -> t=0 outputs. No Dt scaling. mu0 lives in out[t=0].
// conv1 output pos pr maps to gy=ty-1+pr; sIn staged from ty-2 -> index
// pr + k/3 (NO extra offset — the +1 here was round 6's bug).
// ---------------------------------------------------------------------------
__global__ __launch_bounds__(256, 4) void k_dec_init(
    const float* __restrict__ h,
    const float* __restrict__ w1, const float* __restrict__ b1,
    const float* __restrict__ w2, const float* __restrict__ b2,
    float* __restrict__ out) {
  __shared__ float sIn[3][20][20];   //  4.8 KB
  __shared__ float sA[12][18][18];   // 15.2 KB (channel-split, 2 passes)

  const int tid = threadIdx.x;
  const int bb = blockIdx.x >> 6;
  const int tile = blockIdx.x & 63;
  const int ty = (tile >> 3) * 16, tx = (tile & 7) * 16;

  const float* sf = h + (size_t)bb * 3 * kHW;
  for (int idx = tid; idx < 3 * 400; idx += 256) {
    const int ch = idx / 400, rem = idx - ch * 400;
    const int r = rem / 20, c = rem - r * 20;
    const int gy = ty - 2 + r, gx = tx - 2 + c;
    float v = 0.0f;
    if ((unsigned)gy < 128u && (unsigned)gx < 128u)
      v = sf[ch * kHW + gy * 128 + gx];
    sIn[ch][r][c] = v;
  }
  __syncthreads();

  const int r = tid >> 4, c = tid & 15;
  float ft[6];
#pragma unroll
  for (int oc = 0; oc < 6; oc++) ft[oc] = b2[oc];

  for (int pass = 0; pass < 2; ++pass) {
    for (int pos = tid; pos < 18 * 18; pos += 256) {
      const int pr = pos / 18, pc = pos - (pos / 18) * 18;
      const int gy = ty - 1 + pr, gx = tx - 1 + pc;
      const bool inb = ((unsigned)gy < 128u) && ((unsigned)gx < 128u);
      float gv[27];
#pragma unroll
      for (int ic = 0; ic < 3; ic++)
#pragma unroll
        for (int k = 0; k < 9; k++)
          gv[ic * 9 + k] = sIn[ic][pr + k / 3][pc + k % 3];
      for (int ol = 0; ol < 12; ol++) {
        const int oc = pass * 12 + ol;
        float acc = b1[oc];
#pragma unroll
        for (int q = 0; q < 27; q++) acc = fmaf(gv[q], w1[oc * 27 + q], acc);
        sA[ol][pr][pc] = inb ? fmaxf(acc, 0.0f) : 0.0f;
      }
    }
    __syncthreads();

    for (int il = 0; il < 12; il++) {
      const int ic = pass * 12 + il;
      float av[9];
#pragma unroll
      for (int k = 0; k < 9; k++) av[k] = sA[il][r + k / 3][c + k % 3];
#pragma unroll
      for (int oc = 0; oc < 6; oc++)
#pragma unroll
        for (int k = 0; k < 9; k++)
          ft[oc] = fmaf(av[k], w2[(oc * 24 + ic) * 9 + k], ft[oc]);
    }
    __syncthreads();
  }

  {
    const int p = (ty + r) * 128 + (tx + c);
    const size_t ob = ((size_t)(bb * kT + 0) * kHW + p) * 3;
#pragma unroll
    for (int ch = 0; ch < 3; ch++) {
      out[ob + ch] = ft[ch];
      out[kMuElems + ob + ch] = splus01(ft[3 + ch]);
    }
  }
}

// ---------------------------------------------------------------------------
// Fused recurrent cell. Mem(t-1) is read from out's mu block at t-1 (the
// float values stored there are exactly the recurrent state). Writes only
// out[t]. hc is the precomputed diff living in E[t].
// ---------------------------------------------------------------------------
__global__ __launch_bounds__(256, 4) void k_cell(
    const float* __restrict__ E, int t,
    const float* __restrict__ mgw, const float* __restrict__ mgb,
    const float* __restrict__ cw1, const float* __restrict__ cb1,
    const float* __restrict__ cw2, const float* __restrict__ cb2,
    float* __restrict__ out) {
  __shared__ float sIn[6][22][22];   // 11.6 KB
  __shared__ float sG[3][20][20];    //  4.7 KB
  __shared__ float sA[12][18][18];   // 15.2 KB (channel-split, 2 passes)

  const int tid = threadIdx.x;
  const int bb = blockIdx.x >> 6;
  const int tile = blockIdx.x & 63;
  const int ty = (tile >> 3) * 16, tx = (tile & 7) * 16;

  const float* hc = E + (size_t)(bb * kT + t) * 3 * kHW;  // precomputed diff
  const float* prevMu = out + (size_t)(bb * kT + (t - 1)) * kHW * 3;

  // Stage 6x22x22 input (3-halo). Zero outside image.
  for (int idx = tid; idx < 6 * 484; idx += 256) {
    const int ch = idx / 484, rem = idx - ch * 484;
    const int r = rem / 22, c = rem - r * 22;
    const int gy = ty - 3 + r, gx = tx - 3 + c;
    float v = 0.0f;
    if ((unsigned)gy < 128u && (unsigned)gx < 128u) {
      const int p = gy * 128 + gx;
      v = (ch < 3) ? prevMu[p * 3 + ch] : hc[(ch - 3) * kHW + p];
    }
    sIn[ch][r][c] = v;
  }
  __syncthreads();

  // sG = conv(sIn, mg) + bias (no relu), 20x20, zero outside image.
  for (int pos = tid; pos < 20 * 20; pos += 256) {
    const int r = pos / 20, c = pos - (pos / 20) * 20;
    const int gy = ty - 2 + r, gx = tx - 2 + c;
    float a0 = mgb[0], a1 = mgb[1], a2 = mgb[2];
#pragma unroll
    for (int ic = 0; ic < 6; ic++)
#pragma unroll
      for (int k = 0; k < 9; k++) {
        const float v = sIn[ic][r + k / 3][c + k % 3];
        a0 = fmaf(v, mgw[(0 * 6 + ic) * 9 + k], a0);
        a1 = fmaf(v, mgw[(1 * 6 + ic) * 9 + k], a1);
        a2 = fmaf(v, mgw[(2 * 6 + ic) * 9 + k], a2);
      }
    const bool inb = ((unsigned)gy < 128u) && ((unsigned)gx < 128u);
    sG[0][r][c] = inb ? a0 : 0.0f;
    sG[1][r][c] = inb ? a1 : 0.0f;
    sG[2][r][c] = inb ? a2 : 0.0f;
  }
  __syncthreads();

  const int r = tid >> 4, c = tid & 15;
  float ft[6];
#pragma unroll
  for (int oc = 0; oc < 6; oc++) ft[oc] = cb2[oc];

  for (int pass = 0; pass < 2; ++pass) {
    for (int pos = tid; pos < 18 * 18; pos += 256) {
      const int pr = pos / 18, pc = pos - (pos / 18) * 18;
      const int gy = ty - 1 + pr, gx = tx - 1 + pc;
      const bool inb = ((unsigned)gy < 128u) && ((unsigned)gx < 128u);
      float gv[27];
#pragma unroll
      for (int ic = 0; ic < 3; ic++)
#pragma unroll
        for (int k = 0; k < 9; k++)
          gv[ic * 9 + k] = sG[ic][pr + k / 3][pc + k % 3];
      for (int ol = 0; ol < 12; ol++) {
        const int oc = pass * 12 + ol;
        float acc = cb1[oc];
#pragma unroll
        for (int q = 0; q < 27; q++) acc = fmaf(gv[q], cw1[oc * 27 + q], acc);
        sA[ol][pr][pc] = inb ? fmaxf(acc, 0.0f) : 0.0f;
      }
    }
    __syncthreads();

    for (int il = 0; il < 12; il++) {
      const int ic = pass * 12 + il;
      float av[9];
#pragma unroll
      for (int k = 0; k < 9; k++) av[k] = sA[il][r + k / 3][c + k % 3];
#pragma unroll
      for (int oc = 0; oc < 6; oc++)
#pragma unroll
        for (int k = 0; k < 9; k++)
          ft[oc] = fmaf(av[k], cw2[(oc * 24 + ic) * 9 + k], ft[oc]);
    }
    __syncthreads();
  }

  {
    const int p = (ty + r) * 128 + (tx + c);
    const size_t ob = ((size_t)(bb * kT + t) * kHW + p) * 3;
#pragma unroll
    for (int ch = 0; ch < 3; ch++) {
      out[ob + ch] = ft[ch] * kDT;
      out[kMuElems + ob + ch] = splus01(ft[3 + ch] * kDT);
    }
  }
}

}  // namespace

extern "C" void kernel_launch(void* const* d_in, const int* in_sizes, int n_in,
                              void* d_out, int out_size, void* d_ws,
                              size_t ws_size, hipStream_t stream) {
  const float* vids  = (const float*)d_in[0];
  const float* ie_w1 = (const float*)d_in[1];
  const float* ie_b1 = (const float*)d_in[2];
  const float* ie_w2 = (const float*)d_in[3];
  const float* ie_b2 = (const float*)d_in[4];
  const float* id_w1 = (const float*)d_in[5];
  const float* id_b1 = (const float*)d_in[6];
  const float* id_w2 = (const float*)d_in[7];
  const float* id_b2 = (const float*)d_in[8];
  const float* ce_w1 = (const float*)d_in[9];
  const float* ce_b1 = (const float*)d_in[10];
  const float* ce_w2 = (const float*)d_in[11];
  const float* ce_b2 = (const float*)d_in[12];
  const float* cd_w1 = (const float*)d_in[13];
  const float* cd_b1 = (const float*)d_in[14];
  const float* cd_w2 = (const float*)d_in[15];
  const float* cd_b2 = (const float*)d_in[16];
  const float* mg_w  = (const float*)d_in[17];
  const float* mg_b  = (const float*)d_in[18];

  char* ws = (char*)d_ws;
  int* winner = (int*)ws;   ws += (size_t)kNF * kHW * 4;       // 31.5 MB
  float* h    = (float*)ws; ws += (size_t)kB * 3 * kHW * 4;    // 3.1 MB
  float* E    = (float*)ws; ws += (size_t)kNF * 3 * kHW * 4;   // 94.4 MB

  float* out = (float*)d_out;  // float32 (reference output dtype)

  hipMemsetAsync(winner, 0xFF, (size_t)kNF * kHW * 4, stream);
  k_scatter<<<kNF, 256, 0, stream>>>(vids, winner);

  // E[b,t] = enc2(vid_t[b,t]) for all 480 frames (parallel).
  k_enc<5, true><<<kNF * 16, 256, 0, stream>>>(vids, winner, 1, ce_w1, ce_b1,
                                               ce_w2, ce_b2, E);
  // In-place: E[t] <- (E[t-1]-E[t])/Dt  (t>=1).
  k_hc<<<(kB * 3 * kHW + 255) / 256, 256, 0, stream>>>(E);

  // h[b] = init encoder on frame (b, 0).
  k_enc<4, false><<<kB * 16, 256, 0, stream>>>(vids, winner, kT, ie_w1, ie_b1,
                                               ie_w2, ie_b2, h);
  // init decode: t=0 outputs (mu0 doubles as recurrent state in `out`).
  k_dec_init<<<kB * 64, 256, 0, stream>>>(h, id_w1, id_b1, id_w2, id_b2, out);

  // Sequential recurrence; each step reads mu(t-1) from `out`.
  for (int t = 1; t < kT; ++t) {
    k_cell<<<kB * 64, 256, 0, stream>>>(E, t, mg_w, mg_b, cd_w1, cd_b1,
                                        cd_w2, cd_b2, out);
  }
}

// Round 8
// 1275.927 us; speedup vs baseline: 8.2023x; 1.1133x over previous
//
#include <hip/hip_runtime.h>
#include <math.h>

namespace {

constexpr int kT = 30, kS = 1024, kB = 16;
constexpr int kHW = 128 * 128;
constexpr int kNF = kB * kT;                            // 480 frames
constexpr float kDT = (float)(1.0 / 29.0);
constexpr size_t kMuElems = (size_t)kB * kT * kHW * 3;  // 23,592,960 floats

__device__ __forceinline__ float splus01(float x) {
  float sp = (x > 20.0f) ? x : log1pf(expf(x));
  return fminf(fmaxf(sp, 1e-6f), 1.0f);
}

// ---------------------------------------------------------------------------
// Scatter: winner[p] = max point index s mapping to pixel p (last-write-wins
// = numpy sequential assignment). winner pre-set to -1. OOB points dropped.
// ---------------------------------------------------------------------------
__global__ void k_scatter(const float* __restrict__ vids,
                          int* __restrict__ winner) {
  const int f = blockIdx.x;
  const float* fr = vids + (size_t)f * kS * 5;
  int* wf = winner + (size_t)f * kHW;
  for (int s = threadIdx.x; s < kS; s += blockDim.x) {
    const int i = (int)(fr[s * 5 + 0] * 128.0f);
    const int j = (int)(fr[s * 5 + 1] * 128.0f);
    if ((unsigned)i < 128u && (unsigned)j < 128u)
      atomicMax(wf + i * 128 + j, s);
  }
}

// ---------------------------------------------------------------------------
// Encoder pair: conv CIN->3 (+bias, relu) -> conv 3->3 (+bias).
// Tile 16 rows x 32 cols, 256 threads, LDS ~21.5 KB -> 7 blocks/CU.
// Staging is pixel-major: winner read ONCE per pixel, all channels written.
// ---------------------------------------------------------------------------
template <int CIN, bool HAS_T>
__global__ __launch_bounds__(256, 4) void k_enc(
    const float* __restrict__ vids, const int* __restrict__ winner, int fstep,
    const float* __restrict__ w1, const float* __restrict__ b1,
    const float* __restrict__ w2, const float* __restrict__ b2,
    float* __restrict__ out) {
  __shared__ float sIn[CIN][20][36];  // 16+4 x 32+4
  __shared__ float sC1[3][18][34];    // 16+2 x 32+2

  const int tid = threadIdx.x;
  const int f = blockIdx.x >> 5;          // 32 tiles per frame
  const int df = f * fstep;
  const int tile = blockIdx.x & 31;
  const int ty = (tile >> 2) * 16;
  const int tx = (tile & 3) * 32;

  const int* win = winner + (size_t)df * kHW;
  const float* fr = vids + (size_t)df * kS * 5;
  const float tval = HAS_T ? (float)(df % kT) * kDT : 0.0f;

  // Stage 20x36 with 2-halo, pixel-major.
  for (int pix = tid; pix < 20 * 36; pix += 256) {
    const int r = pix / 36, c = pix - r * 36;
    const int gy = ty - 2 + r, gx = tx - 2 + c;
    const bool inb = ((unsigned)gy < 128u) && ((unsigned)gx < 128u);
    int wn = -1;
    if (inb) wn = win[gy * 128 + gx];
    float y0 = 0.0f, y1 = 0.0f, y2 = 0.0f;
    if (wn >= 0) {
      y0 = fminf(fmaxf(fr[wn * 5 + 2], 0.0f), 1.0f);
      y1 = fminf(fmaxf(fr[wn * 5 + 3], 0.0f), 1.0f);
      y2 = fminf(fmaxf(fr[wn * 5 + 4], 0.0f), 1.0f);
    }
    sIn[0][r][c] = y0;
    sIn[1][r][c] = y1;
    sIn[2][r][c] = y2;
    if (HAS_T) {
      sIn[3][r][c] = inb ? tval : 0.0f;
      sIn[CIN - 1][r][c] = (wn >= 0) ? 1.0f : 0.0f;
    } else {
      sIn[CIN - 1][r][c] = (wn >= 0) ? 1.0f : 0.0f;
    }
  }
  __syncthreads();

  // conv1 + relu -> 18x34 (rows ty-1..ty+16). Zero outside image.
  for (int pos = tid; pos < 18 * 34; pos += 256) {
    const int r = pos / 34, c = pos - (pos / 34) * 34;
    const int gy = ty - 1 + r, gx = tx - 1 + c;
    float a0 = b1[0], a1 = b1[1], a2 = b1[2];
#pragma unroll
    for (int ic = 0; ic < CIN; ic++)
#pragma unroll
      for (int k = 0; k < 9; k++) {
        const float v = sIn[ic][r + k / 3][c + k % 3];
        a0 = fmaf(v, w1[(0 * CIN + ic) * 9 + k], a0);
        a1 = fmaf(v, w1[(1 * CIN + ic) * 9 + k], a1);
        a2 = fmaf(v, w1[(2 * CIN + ic) * 9 + k], a2);
      }
    const bool inb = ((unsigned)gy < 128u) && ((unsigned)gx < 128u);
    sC1[0][r][c] = inb ? fmaxf(a0, 0.0f) : 0.0f;
    sC1[1][r][c] = inb ? fmaxf(a1, 0.0f) : 0.0f;
    sC1[2][r][c] = inb ? fmaxf(a2, 0.0f) : 0.0f;
  }
  __syncthreads();

  // conv2 -> 16x32 outputs, planar [3][HW].
  float* of = out + (size_t)f * 3 * kHW;
  for (int pos = tid; pos < 512; pos += 256) {
    const int r = pos >> 5, c = pos & 31;
    float a0 = b2[0], a1 = b2[1], a2 = b2[2];
#pragma unroll
    for (int ic = 0; ic < 3; ic++)
#pragma unroll
      for (int k = 0; k < 9; k++) {
        const float v = sC1[ic][r + k / 3][c + k % 3];
        a0 = fmaf(v, w2[(0 * 3 + ic) * 9 + k], a0);
        a1 = fmaf(v, w2[(1 * 3 + ic) * 9 + k], a1);
        a2 = fmaf(v, w2[(2 * 3 + ic) * 9 + k], a2);
      }
    const int p = (ty + r) * 128 + (tx + c);
    of[p] = a0;
    of[kHW + p] = a1;
    of[2 * kHW + p] = a2;
  }
}

// ---------------------------------------------------------------------------
// In-place temporal difference: E[t] <- (E[t-1] - E[t]) / Dt for t=1..T-1.
// ---------------------------------------------------------------------------
__global__ __launch_bounds__(256) void k_hc(float* __restrict__ E) {
  const int idx = blockIdx.x * 256 + threadIdx.x;
  if (idx >= kB * 3 * kHW) return;
  const int b = idx / (3 * kHW);
  const int rem = idx - b * 3 * kHW;
  float* base = E + (size_t)b * kT * 3 * kHW + rem;
  float prev = base[0];
  for (int t = 1; t < kT; ++t) {
    const size_t o = (size_t)t * 3 * kHW;
    const float cur = base[o];
    base[o] = (prev - cur) / kDT;
    prev = cur;
  }
}

// ---------------------------------------------------------------------------
// Init decode (unchanged from passing round 7): h -> conv 3->24 relu
// (2 passes of 12) -> conv 24->6 -> t=0 outputs. No Dt. mu0 -> out[t=0].
// ---------------------------------------------------------------------------
__global__ __launch_bounds__(256, 4) void k_dec_init(
    const float* __restrict__ h,
    const float* __restrict__ w1, const float* __restrict__ b1,
    const float* __restrict__ w2, const float* __restrict__ b2,
    float* __restrict__ out) {
  __shared__ float sIn[3][20][20];
  __shared__ float sA[12][18][18];

  const int tid = threadIdx.x;
  const int bb = blockIdx.x >> 6;
  const int tile = blockIdx.x & 63;
  const int ty = (tile >> 3) * 16, tx = (tile & 7) * 16;

  const float* sf = h + (size_t)bb * 3 * kHW;
  for (int idx = tid; idx < 3 * 400; idx += 256) {
    const int ch = idx / 400, rem = idx - ch * 400;
    const int r = rem / 20, c = rem - r * 20;
    const int gy = ty - 2 + r, gx = tx - 2 + c;
    float v = 0.0f;
    if ((unsigned)gy < 128u && (unsigned)gx < 128u)
      v = sf[ch * kHW + gy * 128 + gx];
    sIn[ch][r][c] = v;
  }
  __syncthreads();

  const int r = tid >> 4, c = tid & 15;
  float ft[6];
#pragma unroll
  for (int oc = 0; oc < 6; oc++) ft[oc] = b2[oc];

  for (int pass = 0; pass < 2; ++pass) {
    for (int pos = tid; pos < 18 * 18; pos += 256) {
      const int pr = pos / 18, pc = pos - (pos / 18) * 18;
      const int gy = ty - 1 + pr, gx = tx - 1 + pc;
      const bool inb = ((unsigned)gy < 128u) && ((unsigned)gx < 128u);
      float gv[27];
#pragma unroll
      for (int ic = 0; ic < 3; ic++)
#pragma unroll
        for (int k = 0; k < 9; k++)
          gv[ic * 9 + k] = sIn[ic][pr + k / 3][pc + k % 3];
      for (int ol = 0; ol < 12; ol++) {
        const int oc = pass * 12 + ol;
        float acc = b1[oc];
#pragma unroll
        for (int q = 0; q < 27; q++) acc = fmaf(gv[q], w1[oc * 27 + q], acc);
        sA[ol][pr][pc] = inb ? fmaxf(acc, 0.0f) : 0.0f;
      }
    }
    __syncthreads();

    for (int il = 0; il < 12; il++) {
      const int ic = pass * 12 + il;
      float av[9];
#pragma unroll
      for (int k = 0; k < 9; k++) av[k] = sA[il][r + k / 3][c + k % 3];
#pragma unroll
      for (int oc = 0; oc < 6; oc++)
#pragma unroll
        for (int k = 0; k < 9; k++)
          ft[oc] = fmaf(av[k], w2[(oc * 24 + ic) * 9 + k], ft[oc]);
    }
    __syncthreads();
  }

  {
    const int p = (ty + r) * 128 + (tx + c);
    const size_t ob = ((size_t)(bb * kT + 0) * kHW + p) * 3;
#pragma unroll
    for (int ch = 0; ch < 3; ch++) {
      out[ob + ch] = ft[ch];
      out[kMuElems + ob + ch] = splus01(ft[3 + ch]);
    }
  }
}

// ---------------------------------------------------------------------------
// Fused recurrent cell, small-tile high-occupancy version.
// Tile 8 rows x 16 cols, 128 threads, LDS ~18.5 KB -> 8 blocks/CU resident
// (grid 2048 = exactly 8/CU). Halo chain 14x22 -> 12x20 -> 10x18 -> 8x16.
// Mem(t-1) read from out's mu block at t-1; writes out[t] only.
// ---------------------------------------------------------------------------
__global__ __launch_bounds__(128, 4) void k_cell(
    const float* __restrict__ E, int t,
    const float* __restrict__ mgw, const float* __restrict__ mgb,
    const float* __restrict__ cw1, const float* __restrict__ cb1,
    const float* __restrict__ cw2, const float* __restrict__ cb2,
    float* __restrict__ out) {
  __shared__ float sIn[6][14][22];   // 7.2 KB
  __shared__ float sG[3][12][20];    // 2.8 KB
  __shared__ float sA[12][10][18];   // 8.4 KB (channel-split, 2 passes)

  const int tid = threadIdx.x;
  const int bb = blockIdx.x >> 7;          // 128 tiles per batch elem
  const int tile = blockIdx.x & 127;
  const int ty = (tile >> 3) * 8;          // 16 row-tiles
  const int tx = (tile & 7) * 16;          // 8 col-tiles

  const float* hc = E + (size_t)(bb * kT + t) * 3 * kHW;  // precomputed diff
  const float* prevMu = out + (size_t)(bb * kT + (t - 1)) * kHW * 3;

  // Stage 6 x 14x22 (3-halo), pixel-major: mu interleaved + hc planar.
  for (int pix = tid; pix < 14 * 22; pix += 128) {
    const int r = pix / 22, c = pix - r * 22;
    const int gy = ty - 3 + r, gx = tx - 3 + c;
    float m0 = 0.0f, m1 = 0.0f, m2 = 0.0f, h0 = 0.0f, h1 = 0.0f, h2 = 0.0f;
    if ((unsigned)gy < 128u && (unsigned)gx < 128u) {
      const int p = gy * 128 + gx;
      m0 = prevMu[p * 3 + 0];
      m1 = prevMu[p * 3 + 1];
      m2 = prevMu[p * 3 + 2];
      h0 = hc[0 * kHW + p];
      h1 = hc[1 * kHW + p];
      h2 = hc[2 * kHW + p];
    }
    sIn[0][r][c] = m0;
    sIn[1][r][c] = m1;
    sIn[2][r][c] = m2;
    sIn[3][r][c] = h0;
    sIn[4][r][c] = h1;
    sIn[5][r][c] = h2;
  }
  __syncthreads();

  // sG = conv(sIn, mg) + bias (no relu), 12x20, zero outside image.
  for (int pos = tid; pos < 12 * 20; pos += 128) {
    const int r = pos / 20, c = pos - (pos / 20) * 20;
    const int gy = ty - 2 + r, gx = tx - 2 + c;
    float a0 = mgb[0], a1 = mgb[1], a2 = mgb[2];
#pragma unroll
    for (int ic = 0; ic < 6; ic++)
#pragma unroll
      for (int k = 0; k < 9; k++) {
        const float v = sIn[ic][r + k / 3][c + k % 3];
        a0 = fmaf(v, mgw[(0 * 6 + ic) * 9 + k], a0);
        a1 = fmaf(v, mgw[(1 * 6 + ic) * 9 + k], a1);
        a2 = fmaf(v, mgw[(2 * 6 + ic) * 9 + k], a2);
      }
    const bool inb = ((unsigned)gy < 128u) && ((unsigned)gx < 128u);
    sG[0][r][c] = inb ? a0 : 0.0f;
    sG[1][r][c] = inb ? a1 : 0.0f;
    sG[2][r][c] = inb ? a2 : 0.0f;
  }
  __syncthreads();

  const int r = tid >> 4, c = tid & 15;  // 8x16 output pixel of this thread
  float ft[6];
#pragma unroll
  for (int oc = 0; oc < 6; oc++) ft[oc] = cb2[oc];

  for (int pass = 0; pass < 2; ++pass) {
    // cd1: 12 channels of relu(conv3->24) on 10x18.
    for (int pos = tid; pos < 10 * 18; pos += 128) {
      const int pr = pos / 18, pc = pos - (pos / 18) * 18;
      const int gy = ty - 1 + pr, gx = tx - 1 + pc;
      const bool inb = ((unsigned)gy < 128u) && ((unsigned)gx < 128u);
      float gv[27];
#pragma unroll
      for (int ic = 0; ic < 3; ic++)
#pragma unroll
        for (int k = 0; k < 9; k++)
          gv[ic * 9 + k] = sG[ic][pr + k / 3][pc + k % 3];
      for (int ol = 0; ol < 12; ol++) {
        const int oc = pass * 12 + ol;
        float acc = cb1[oc];
#pragma unroll
        for (int q = 0; q < 27; q++) acc = fmaf(gv[q], cw1[oc * 27 + q], acc);
        sA[ol][pr][pc] = inb ? fmaxf(acc, 0.0f) : 0.0f;
      }
    }
    __syncthreads();

    // cd2: accumulate this pass's 12 input channels into ft.
    for (int il = 0; il < 12; il++) {
      const int ic = pass * 12 + il;
      float av[9];
#pragma unroll
      for (int k = 0; k < 9; k++) av[k] = sA[il][r + k / 3][c + k % 3];
#pragma unroll
      for (int oc = 0; oc < 6; oc++)
#pragma unroll
        for (int k = 0; k < 9; k++)
          ft[oc] = fmaf(av[k], cw2[(oc * 24 + ic) * 9 + k], ft[oc]);
    }
    __syncthreads();
  }

  {
    const int p = (ty + r) * 128 + (tx + c);
    const size_t ob = ((size_t)(bb * kT + t) * kHW + p) * 3;
#pragma unroll
    for (int ch = 0; ch < 3; ch++) {
      out[ob + ch] = ft[ch] * kDT;
      out[kMuElems + ob + ch] = splus01(ft[3 + ch] * kDT);
    }
  }
}

}  // namespace

extern "C" void kernel_launch(void* const* d_in, const int* in_sizes, int n_in,
                              void* d_out, int out_size, void* d_ws,
                              size_t ws_size, hipStream_t stream) {
  const float* vids  = (const float*)d_in[0];
  const float* ie_w1 = (const float*)d_in[1];
  const float* ie_b1 = (const float*)d_in[2];
  const float* ie_w2 = (const float*)d_in[3];
  const float* ie_b2 = (const float*)d_in[4];
  const float* id_w1 = (const float*)d_in[5];
  const float* id_b1 = (const float*)d_in[6];
  const float* id_w2 = (const float*)d_in[7];
  const float* id_b2 = (const float*)d_in[8];
  const float* ce_w1 = (const float*)d_in[9];
  const float* ce_b1 = (const float*)d_in[10];
  const float* ce_w2 = (const float*)d_in[11];
  const float* ce_b2 = (const float*)d_in[12];
  const float* cd_w1 = (const float*)d_in[13];
  const float* cd_b1 = (const float*)d_in[14];
  const float* cd_w2 = (const float*)d_in[15];
  const float* cd_b2 = (const float*)d_in[16];
  const float* mg_w  = (const float*)d_in[17];
  const float* mg_b  = (const float*)d_in[18];

  char* ws = (char*)d_ws;
  int* winner = (int*)ws;   ws += (size_t)kNF * kHW * 4;       // 31.5 MB
  float* h    = (float*)ws; ws += (size_t)kB * 3 * kHW * 4;    // 3.1 MB
  float* E    = (float*)ws; ws += (size_t)kNF * 3 * kHW * 4;   // 94.4 MB

  float* out = (float*)d_out;  // float32 (reference output dtype)

  hipMemsetAsync(winner, 0xFF, (size_t)kNF * kHW * 4, stream);
  k_scatter<<<kNF, 256, 0, stream>>>(vids, winner);

  // E[b,t] = enc2(vid_t[b,t]) for all 480 frames (parallel, 32 tiles each).
  k_enc<5, true><<<kNF * 32, 256, 0, stream>>>(vids, winner, 1, ce_w1, ce_b1,
                                               ce_w2, ce_b2, E);
  // In-place: E[t] <- (E[t-1]-E[t])/Dt  (t>=1).
  k_hc<<<(kB * 3 * kHW + 255) / 256, 256, 0, stream>>>(E);

  // h[b] = init encoder on frame (b, 0).
  k_enc<4, false><<<kB * 32, 256, 0, stream>>>(vids, winner, kT, ie_w1, ie_b1,
                                               ie_w2, ie_b2, h);
  // init decode: t=0 outputs (mu0 doubles as recurrent state in `out`).
  k_dec_init<<<kB * 64, 256, 0, stream>>>(h, id_w1, id_b1, id_w2, id_b2, out);

  // Sequential recurrence; each step reads mu(t-1) from `out`.
  for (int t = 1; t < kT; ++t) {
    k_cell<<<kB * 128, 128, 0, stream>>>(E, t, mg_w, mg_b, cd_w1, cd_b1,
                                         cd_w2, cd_b2, out);
  }
}